// Round 4
// baseline (945.750 us; speedup 1.0000x reference)
//
#include <hip/hip_runtime.h>

#define TS 1000

__device__ __forceinline__ float rl(float v, int lane) {
    return __int_as_float(__builtin_amdgcn_readlane(__float_as_int(v), lane));
}
__device__ __forceinline__ float fsig(float x) {
    return __builtin_amdgcn_rcpf(1.0f + __expf(-x));
}
__device__ __forceinline__ float ftanh(float x) {
    return 1.0f - 2.0f * __builtin_amdgcn_rcpf(1.0f + __expf(2.0f * x));
}

// ---------------- Phase 1: gx[g][b][t][192] = x[b][t][g*64..] @ W[g] + b_i[g]
// grid (16 t-tiles, 32 b, 8 g), 256 threads. (unchanged — known good, ~189 us)
__global__ __launch_bounds__(256)
void gx_gemm(const float* __restrict__ x, const float* __restrict__ W,
             const float* __restrict__ bi, float* __restrict__ gx)
{
    const int g = blockIdx.z, b = blockIdx.y, t0 = blockIdx.x * 64;
    const int rows = (TS - t0 < 64) ? (TS - t0) : 64;

    __shared__ float xt[64][64];
    const float* xrow = x + (size_t)b * (TS * 512) + g * 64;
    for (int idx = threadIdx.x; idx < 64 * 64; idx += 256) {
        const int r = idx >> 6, k = idx & 63;
        const int t = t0 + ((r < rows) ? r : (rows - 1));
        xt[r][k] = xrow[(size_t)t * 512 + k];
    }
    __syncthreads();

    const int tr = threadIdx.x >> 6, tc = threadIdx.x & 63;
    float acc[16][3];
    {
        const float b0 = bi[g * 192 + tc], b1 = bi[g * 192 + 64 + tc], b2 = bi[g * 192 + 128 + tc];
        #pragma unroll
        for (int i = 0; i < 16; ++i) { acc[i][0] = b0; acc[i][1] = b1; acc[i][2] = b2; }
    }
    const float* Wg = W + (size_t)g * (64 * 192);
    #pragma unroll 4
    for (int k = 0; k < 64; ++k) {
        const float w0 = Wg[k * 192 + tc];
        const float w1 = Wg[k * 192 + 64 + tc];
        const float w2 = Wg[k * 192 + 128 + tc];
        #pragma unroll
        for (int i = 0; i < 16; ++i) {
            const float xv = xt[tr * 16 + i][k];   // uniform per wave -> LDS broadcast
            acc[i][0] = fmaf(xv, w0, acc[i][0]);
            acc[i][1] = fmaf(xv, w1, acc[i][1]);
            acc[i][2] = fmaf(xv, w2, acc[i][2]);
        }
    }
    float* gp = gx + ((size_t)(g * 32 + b) * TS + t0) * 192;
    #pragma unroll
    for (int i = 0; i < 16; ++i) {
        const int r = tr * 16 + i;
        if (r < rows) {
            gp[(size_t)r * 192 + tc]       = acc[i][0];
            gp[(size_t)r * 192 + 64 + tc]  = acc[i][1];
            gp[(size_t)r * 192 + 128 + tc] = acc[i][2];
        }
    }
}

// ---------------- Phase 2: serial recurrence. ONE wave per (g,b) chain.
// No LDS, no barriers, bitwise deterministic. amdgpu_waves_per_eu(1,1):
// tell scheduler+RA that occupancy IS 1 wave/EU, so it may hold ~230 VGPRs
// live (192 stationary U weights) instead of spilling to scratch/AGPR —
// launch_bounds' min-waves alone did not stop the occupancy heuristic
// (observed VGPR_Count=108 with ~280 extra reload ops/step).
__global__ __launch_bounds__(64)
__attribute__((amdgpu_waves_per_eu(1, 1)))
void gru_seq(const float* __restrict__ gx, const float* __restrict__ h0,
             const float* __restrict__ U, const float* __restrict__ bh,
             float* __restrict__ out, float* __restrict__ hout)
{
    const int g = blockIdx.x >> 5, b = blockIdx.x & 31;
    const int lane = threadIdx.x;

    float u0[64], u1[64], u2[64];
    {
        const float* Ug = U + (size_t)g * (64 * 192) + lane;
        #pragma unroll
        for (int k = 0; k < 64; ++k) {
            u0[k] = Ug[k * 192];
            u1[k] = Ug[k * 192 + 64];
            u2[k] = Ug[k * 192 + 128];
        }
    }
    // Pin: asm-defined values cannot be re-formed by reloading.
    #pragma unroll
    for (int k = 0; k < 64; ++k)
        asm volatile("" : "+v"(u0[k]), "+v"(u1[k]), "+v"(u2[k]));

    const float bz = bh[g * 192 + lane];
    const float br = bh[g * 192 + 64 + lane];
    const float bn = bh[g * 192 + 128 + lane];

    float h = h0[(g * 32 + b) * 64 + lane];

    const float* gp = gx + (size_t)(g * 32 + b) * (TS * 192);
    float cz  = gp[lane],        crr = gp[64 + lane],  cn  = gp[128 + lane];
    float n1z = gp[192 + lane],  n1r = gp[256 + lane], n1n = gp[320 + lane];
    float n2z, n2r, n2n;

    float* op = out + (size_t)b * (TS * 512) + g * 64 + lane;

    for (int t = 0; t < TS; ++t) {
        // prefetch gx(t+2)
        {
            const int tp = (t + 2 < TS) ? (t + 2) : (TS - 1);
            const float* pp = gp + (size_t)tp * 192;
            n2z = pp[lane]; n2r = pp[64 + lane]; n2n = pp[128 + lane];
        }
        float az = bz, ar = br, an = bn;
        #pragma unroll
        for (int k = 0; k < 64; ++k) {
            const float s = rl(h, k);
            az = fmaf(s, u0[k], az);
            ar = fmaf(s, u1[k], ar);
            an = fmaf(s, u2[k], an);
        }
        const float z = fsig(cz + az);
        const float r = fsig(crr + ar);
        const float n = ftanh(fmaf(r, an, cn));   // reset_after: r * (h@U_n + b_h_n)
        h = n + z * (h - n);
        op[(size_t)t * 512] = h;

        cz = n1z; crr = n1r; cn = n1n;
        n1z = n2z; n1r = n2r; n1n = n2n;
    }
    hout[(g * 32 + b) * 64 + lane] = h;
}

// ---------------- Fallback (ws too small): fused single-wave, both matmuls inline.
__global__ __launch_bounds__(64)
__attribute__((amdgpu_waves_per_eu(1, 1)))
void gru_fused1(const float* __restrict__ x, const float* __restrict__ h0,
                const float* __restrict__ W, const float* __restrict__ U,
                const float* __restrict__ bi, const float* __restrict__ bh,
                float* __restrict__ out, float* __restrict__ hout)
{
    const int g = blockIdx.x >> 5, b = blockIdx.x & 31;
    const int lane = threadIdx.x;

    float u[64][3], w[64][3];
    {
        const float* Ug = U + (size_t)g * (64 * 192) + lane;
        const float* Wg = W + (size_t)g * (64 * 192) + lane;
        #pragma unroll
        for (int k = 0; k < 64; ++k) {
            u[k][0] = Ug[k * 192]; u[k][1] = Ug[k * 192 + 64]; u[k][2] = Ug[k * 192 + 128];
            w[k][0] = Wg[k * 192]; w[k][1] = Wg[k * 192 + 64]; w[k][2] = Wg[k * 192 + 128];
        }
    }
    #pragma unroll
    for (int k = 0; k < 64; ++k) {
        asm volatile("" : "+v"(u[k][0]), "+v"(u[k][1]), "+v"(u[k][2]));
        asm volatile("" : "+v"(w[k][0]), "+v"(w[k][1]), "+v"(w[k][2]));
    }
    const float biz = bi[g * 192 + lane], bir = bi[g * 192 + 64 + lane], bin_ = bi[g * 192 + 128 + lane];
    const float bhz = bh[g * 192 + lane], bhr = bh[g * 192 + 64 + lane], bhn = bh[g * 192 + 128 + lane];

    float h = h0[(g * 32 + b) * 64 + lane];
    const float* xp = x + (size_t)b * (TS * 512) + g * 64 + lane;
    float xc = xp[0], x1 = xp[512], x2;

    float* op = out + (size_t)b * (TS * 512) + g * 64 + lane;

    for (int t = 0; t < TS; ++t) {
        {
            const int tp = (t + 2 < TS) ? (t + 2) : (TS - 1);
            x2 = xp[(size_t)tp * 512];
        }
        float axz = biz, axr = bir, axn = bin_;
        float ahz = bhz, ahr = bhr, ahn = bhn;
        #pragma unroll
        for (int k = 0; k < 64; ++k) {
            const float sx = rl(xc, k);
            axz = fmaf(sx, w[k][0], axz);
            axr = fmaf(sx, w[k][1], axr);
            axn = fmaf(sx, w[k][2], axn);
        }
        #pragma unroll
        for (int k = 0; k < 64; ++k) {
            const float sh = rl(h, k);
            ahz = fmaf(sh, u[k][0], ahz);
            ahr = fmaf(sh, u[k][1], ahr);
            ahn = fmaf(sh, u[k][2], ahn);
        }
        const float z = fsig(axz + ahz);
        const float r = fsig(axr + ahr);
        const float n = ftanh(fmaf(r, ahn, axn));
        h = n + z * (h - n);
        op[(size_t)t * 512] = h;
        xc = x1; x1 = x2;
    }
    hout[(g * 32 + b) * 64 + lane] = h;
}

extern "C" void kernel_launch(void* const* d_in, const int* in_sizes, int n_in,
                              void* d_out, int out_size, void* d_ws, size_t ws_size,
                              hipStream_t stream) {
    const float* x  = (const float*)d_in[0];
    const float* h0 = (const float*)d_in[1];
    const float* W  = (const float*)d_in[2];
    const float* U  = (const float*)d_in[3];
    const float* bi = (const float*)d_in[4];
    const float* bh = (const float*)d_in[5];
    float* out  = (float*)d_out;
    float* hout = out + (size_t)32 * TS * 512;

    const size_t gx_bytes = (size_t)8 * 32 * TS * 192 * sizeof(float);
    if (ws_size >= gx_bytes) {
        float* gx = (float*)d_ws;
        hipLaunchKernelGGL(gx_gemm, dim3(16, 32, 8), dim3(256), 0, stream, x, W, bi, gx);
        hipLaunchKernelGGL(gru_seq, dim3(256), dim3(64), 0, stream, gx, h0, U, bh, out, hout);
    } else {
        hipLaunchKernelGGL(gru_fused1, dim3(256), dim3(64), 0, stream,
                           x, h0, W, U, bi, bh, out, hout);
    }
}

// Round 5
// 689.120 us; speedup vs baseline: 1.3724x; 1.3724x over previous
//
#include <hip/hip_runtime.h>

#define TS 1000

__device__ __forceinline__ float rl(float v, int l) {
    return __int_as_float(__builtin_amdgcn_readlane(__float_as_int(v), l));
}
__device__ __forceinline__ float fsig(float x) {
    return __builtin_amdgcn_rcpf(1.0f + __expf(-x));
}
__device__ __forceinline__ float ftanh(float x) {
    return 1.0f - 2.0f * __builtin_amdgcn_rcpf(1.0f + __expf(2.0f * x));
}

// One block per (g,b) chain, 4 waves:
//   wid0/wid1 = consumers (U·h), K-halves [0,32)/[32,64)
//   wid2/wid3 = producers (W·x(t+1)), K-halves [0,32)/[32,64)
// 96 stationary weights/lane (under the ~130-VGPR residency cap observed in
// rounds 2-4, so nothing spills). One barrier per step; all cross-wave data
// goes through mod-4 ring-buffered LDS slots: written pre-barrier(t), read
// post-barrier(t), earliest rewrite >= 2 barriers after the last read.
// Both consumer waves compute gates redundantly (fixed commutative add order)
// so h never crosses waves -> bitwise deterministic.
__global__ __launch_bounds__(256, 1)
__attribute__((amdgpu_waves_per_eu(1, 1)))
void gru_fused4(const float* __restrict__ x, const float* __restrict__ h0,
                const float* __restrict__ W, const float* __restrict__ U,
                const float* __restrict__ bi, const float* __restrict__ bh,
                float* __restrict__ out, float* __restrict__ hout)
{
    __shared__ float4 cpart[4][2][64];   // consumer partials, slot = t & 3
    __shared__ float4 ppart[4][2][64];   // producer partials, slot = (t+1) & 3 holds gx(t+1)

    const int tid  = threadIdx.x;
    const int lane = tid & 63;
    const int wid  = tid >> 6;
    const int kh   = wid & 1;
    const int role = wid >> 1;          // 0 = consumer (U,h), 1 = producer (W,x)
    const int kbase = __builtin_amdgcn_readfirstlane(kh * 32);

    const int g = blockIdx.x >> 5, b = blockIdx.x & 31;

    // 96 stationary weights per lane: rows kbase..kbase+31, 3 gate columns.
    float w0[32], w1[32], w2[32];
    {
        const float* P = ((role == 0) ? U : W) + (size_t)g * (64 * 192) + (size_t)kbase * 192 + lane;
        #pragma unroll
        for (int k = 0; k < 32; ++k) {
            w0[k] = P[k * 192];
            w1[k] = P[k * 192 + 64];
            w2[k] = P[k * 192 + 128];
        }
    }
    #pragma unroll
    for (int k = 0; k < 32; ++k)
        asm volatile("" : "+v"(w0[k]), "+v"(w1[k]), "+v"(w2[k]));

    // Biases folded into kh0 accumulator init (kh1 starts at 0).
    float bz = 0.f, br = 0.f, bn = 0.f;
    if (kh == 0) {
        const float* bb = ((role == 0) ? bh : bi) + g * 192 + lane;
        bz = bb[0]; br = bb[64]; bn = bb[128];
    }

    float h = 0.f;
    if (role == 0) h = h0[(g * 32 + b) * 64 + lane];

    const float* xp = x + (size_t)b * (TS * 512) + g * 64 + lane;
    float xc = 0.f, xn1 = 0.f, xn2 = 0.f;

    // ---- prologue: producers compute gx(0) -> ppart[0]; prefetch x(1..3)
    if (role == 1) {
        const float x0 = xp[0];
        float az = bz, ar = br, an = bn;
        #pragma unroll
        for (int k = 0; k < 32; ++k) {
            const float s = rl(x0, kbase + k);
            az = fmaf(s, w0[k], az);
            ar = fmaf(s, w1[k], ar);
            an = fmaf(s, w2[k], an);
        }
        ppart[0][kh][lane] = make_float4(az, ar, an, 0.f);
        xc  = xp[512];                    // x(1)
        xn1 = xp[(size_t)2 * 512];        // x(2)
        xn2 = xp[(size_t)3 * 512];        // x(3)
    }
    __syncthreads();

    float* op = out + (size_t)b * (TS * 512) + g * 64 + lane;

    for (int t = 0; t < TS; ++t) {
        // ---- compute own partial (consumers: U·h(t); producers: W·x(t+1))
        const float src = (role == 0) ? h : xc;
        float az = bz, ar = br, an = bn;
        #pragma unroll
        for (int k = 0; k < 32; ++k) {
            const float s = rl(src, kbase + k);
            az = fmaf(s, w0[k], az);
            ar = fmaf(s, w1[k], ar);
            an = fmaf(s, w2[k], an);
        }
        if (role == 0) cpart[t & 3][kh][lane]       = make_float4(az, ar, an, 0.f);
        else           ppart[(t + 1) & 3][kh][lane] = make_float4(az, ar, an, 0.f);

        if (role == 1) {  // rotate x prefetch, ~2 steps (>1100 cyc) in flight
            xc = xn1; xn1 = xn2;
            const int tp = (t + 4 < TS) ? (t + 4) : (TS - 1);
            xn2 = xp[(size_t)tp * 512];
        }
        __syncthreads();

        // ---- consumers: combine partials, gates, update h (redundant in both waves)
        if (role == 0) {
            const float4 oc = cpart[t & 3][kh ^ 1][lane];
            const float4 p0 = ppart[t & 3][0][lane];
            const float4 p1 = ppart[t & 3][1][lane];
            const float ghz = az + oc.x, ghr = ar + oc.y, ghn = an + oc.z;
            const float gxz = p0.x + p1.x, gxr = p0.y + p1.y, gxn = p0.z + p1.z;
            const float z = fsig(gxz + ghz);
            const float r = fsig(gxr + ghr);
            const float n = ftanh(fmaf(r, ghn, gxn));   // reset_after: r * (h@U_n + b_h_n)
            h = n + z * (h - n);
            if (kh == 0) op[(size_t)t * 512] = h;
        }
    }

    if (role == 0 && kh == 0)
        hout[(g * 32 + b) * 64 + lane] = h;
}

extern "C" void kernel_launch(void* const* d_in, const int* in_sizes, int n_in,
                              void* d_out, int out_size, void* d_ws, size_t ws_size,
                              hipStream_t stream) {
    const float* x  = (const float*)d_in[0];
    const float* h0 = (const float*)d_in[1];
    const float* W  = (const float*)d_in[2];
    const float* U  = (const float*)d_in[3];
    const float* bi = (const float*)d_in[4];
    const float* bh = (const float*)d_in[5];
    float* out  = (float*)d_out;
    float* hout = out + (size_t)32 * TS * 512;
    hipLaunchKernelGGL(gru_fused4, dim3(256), dim3(256), 0, stream,
                       x, h0, W, U, bi, bh, out, hout);
}

// Round 6
// 684.837 us; speedup vs baseline: 1.3810x; 1.0063x over previous
//
#include <hip/hip_runtime.h>

#define TS 1000

__device__ __forceinline__ float rl(float v, int l) {
    return __int_as_float(__builtin_amdgcn_readlane(__float_as_int(v), l));
}
__device__ __forceinline__ float fsig(float x) {
    return __builtin_amdgcn_rcpf(1.0f + __expf(-x));
}
__device__ __forceinline__ float ftanh(float x) {
    return 1.0f - 2.0f * __builtin_amdgcn_rcpf(1.0f + __expf(2.0f * x));
}

// ---------------- Phase 1: gx[g][b][t][192] = x[b][t][g*64..] @ W[g] + b_i[g]
// 128-row t-tiles, 512 threads, float4 staging. grid (8, 32, 8).
__global__ __launch_bounds__(512)
void gx_gemm(const float* __restrict__ x, const float* __restrict__ W,
             const float* __restrict__ bi, float* __restrict__ gx)
{
    const int g = blockIdx.z, b = blockIdx.y, t0 = blockIdx.x * 128;
    const int rows = (TS - t0 < 128) ? (TS - t0) : 128;
    const int tid = threadIdx.x;

    __shared__ float xt[128][64];
    const float* xrow = x + (size_t)b * (TS * 512) + g * 64;
    #pragma unroll
    for (int i = 0; i < 4; ++i) {
        const int idx = tid + i * 512;           // 2048 float4 total
        const int r = idx >> 4, c = (idx & 15) << 2;
        const int t = t0 + ((r < rows) ? r : (rows - 1));
        *(float4*)&xt[r][c] = *(const float4*)&xrow[(size_t)t * 512 + c];
    }
    __syncthreads();

    const int tr = tid >> 6, tc = tid & 63;      // 8 waves x 16 rows each
    float acc[16][3];
    {
        const float b0 = bi[g * 192 + tc], b1 = bi[g * 192 + 64 + tc], b2 = bi[g * 192 + 128 + tc];
        #pragma unroll
        for (int i = 0; i < 16; ++i) { acc[i][0] = b0; acc[i][1] = b1; acc[i][2] = b2; }
    }
    const float* Wg = W + (size_t)g * (64 * 192);
    #pragma unroll 4
    for (int k = 0; k < 64; ++k) {
        const float w0 = Wg[k * 192 + tc];
        const float w1 = Wg[k * 192 + 64 + tc];
        const float w2 = Wg[k * 192 + 128 + tc];
        #pragma unroll
        for (int i = 0; i < 16; ++i) {
            const float xv = xt[tr * 16 + i][k];
            acc[i][0] = fmaf(xv, w0, acc[i][0]);
            acc[i][1] = fmaf(xv, w1, acc[i][1]);
            acc[i][2] = fmaf(xv, w2, acc[i][2]);
        }
    }
    float* gp = gx + ((size_t)(g * 32 + b) * TS + t0) * 192;
    #pragma unroll
    for (int i = 0; i < 16; ++i) {
        const int r = tr * 16 + i;
        if (r < rows) {
            gp[(size_t)r * 192 + tc]       = acc[i][0];
            gp[(size_t)r * 192 + 64 + tc]  = acc[i][1];
            gp[(size_t)r * 192 + 128 + tc] = acc[i][2];
        }
    }
}

// ---------------- Phase 2: serial recurrence, 4 waves/block, K-split 16.
// Non-draining __builtin_amdgcn_s_barrier (loads stay in flight across it);
// gx prefetched 2 steps deep via inline-asm loads into 4 statically-indexed
// register sets; consumption gated by s_waitcnt vmcnt(6) TIED to the consumed
// regs ("+v") so uses cannot be hoisted above the wait. All 4 waves compute
// gates redundantly in a fixed sum order -> bitwise-identical h, deterministic.
// LDS partials double-buffered: write slot(t&1) pre-barrier(t), read post-
// barrier(t); rewrite of a slot is 2 barriers after its last read.
__global__ __launch_bounds__(256)
__attribute__((amdgpu_waves_per_eu(1, 1)))
void gru_seq4(const float* __restrict__ gx, const float* __restrict__ h0,
              const float* __restrict__ U, const float* __restrict__ bh,
              float* __restrict__ out, float* __restrict__ hout)
{
    __shared__ float4 part[2][4][64];

    const int tid = threadIdx.x;
    const int lane = tid & 63;
    const int wid = tid >> 6;
    const int kb = __builtin_amdgcn_readfirstlane(wid * 16);

    const int g = blockIdx.x >> 5, b = blockIdx.x & 31;

    // 48 stationary weights/lane: k-rows kb..kb+15, 3 gate columns.
    float w0[16], w1[16], w2[16];
    {
        const float* Ug = U + (size_t)g * (64 * 192) + (size_t)kb * 192 + lane;
        #pragma unroll
        for (int k = 0; k < 16; ++k) {
            w0[k] = Ug[k * 192];
            w1[k] = Ug[k * 192 + 64];
            w2[k] = Ug[k * 192 + 128];
        }
    }
    #pragma unroll
    for (int k = 0; k < 16; ++k)
        asm volatile("" : "+v"(w0[k]), "+v"(w1[k]), "+v"(w2[k]));

    // Recurrent bias folded into wave 0's partial only.
    float bz = 0.f, br = 0.f, bn = 0.f;
    if (wid == 0) {
        bz = bh[g * 192 + lane];
        br = bh[g * 192 + 64 + lane];
        bn = bh[g * 192 + 128 + lane];
    }

    float h = h0[(g * 32 + b) * 64 + lane];   // replicated in all 4 waves

    const float* gp = gx + (size_t)(g * 32 + b) * (TS * 192);
    float* op = out + (size_t)b * (TS * 512) + g * 64 + lane;

    // 4 gx register sets (z,r,n each), written ONLY by asm loads, read only
    // after the tied vmcnt wait. Static indexing via 4x-unrolled t-loop.
    float s0z = 0.f, s0r = 0.f, s0n = 0.f, s1z = 0.f, s1r = 0.f, s1n = 0.f;
    float s2z = 0.f, s2r = 0.f, s2n = 0.f, s3z = 0.f, s3r = 0.f, s3n = 0.f;

#define GXLOAD(PZ, PR, PN, PP)                                               \
    asm volatile("global_load_dword %0, %3, off\n\t"                         \
                 "global_load_dword %1, %3, off offset:256\n\t"              \
                 "global_load_dword %2, %3, off offset:512"                  \
                 : "=v"(PZ), "=v"(PR), "=v"(PN) : "v"(PP));

    { const float* pp = gp + lane;       GXLOAD(s0z, s0r, s0n, pp) }  // t=0
    { const float* pp = gp + 192 + lane; GXLOAD(s1z, s1r, s1n, pp) }  // t=1

#define BODY(J, CZ, CR, CN, PZ, PR, PN)                                      \
    {                                                                        \
        const int t = tt + (J);                                              \
        int tp = t + 2; if (tp > TS - 1) tp = TS - 1;                        \
        const float* pp = gp + (size_t)tp * 192 + lane;                      \
        GXLOAD(PZ, PR, PN, pp)                                               \
        float az = bz, ar = br, an = bn;                                     \
        _Pragma("unroll")                                                    \
        for (int k = 0; k < 16; ++k) {                                       \
            const float s = rl(h, kb + k);                                   \
            az = fmaf(s, w0[k], az);                                         \
            ar = fmaf(s, w1[k], ar);                                         \
            an = fmaf(s, w2[k], an);                                         \
        }                                                                    \
        part[(J) & 1][wid][lane] = make_float4(az, ar, an, 0.f);             \
        asm volatile("s_waitcnt lgkmcnt(0)" ::: "memory");                   \
        __builtin_amdgcn_sched_barrier(0);                                   \
        __builtin_amdgcn_s_barrier();        /* NO vmcnt drain */            \
        __builtin_amdgcn_sched_barrier(0);                                   \
        const float4 p0 = part[(J) & 1][0][lane];                            \
        const float4 p1 = part[(J) & 1][1][lane];                            \
        const float4 p2 = part[(J) & 1][2][lane];                            \
        const float4 p3 = part[(J) & 1][3][lane];                            \
        asm volatile("s_waitcnt vmcnt(6)" : "+v"(CZ), "+v"(CR), "+v"(CN));   \
        const float hz = ((p0.x + p1.x) + p2.x) + p3.x;                      \
        const float hr = ((p0.y + p1.y) + p2.y) + p3.y;                      \
        const float hn = ((p0.z + p1.z) + p2.z) + p3.z;                      \
        const float z = fsig(CZ + hz);                                       \
        const float r = fsig(CR + hr);                                       \
        const float n = ftanh(fmaf(r, hn, CN));  /* reset_after */           \
        h = n + z * (h - n);                                                 \
        if (wid == 0) op[(size_t)t * 512] = h;                               \
    }

    for (int tt = 0; tt < TS; tt += 4) {
        BODY(0, s0z, s0r, s0n, s2z, s2r, s2n)
        BODY(1, s1z, s1r, s1n, s3z, s3r, s3n)
        BODY(2, s2z, s2r, s2n, s0z, s0r, s0n)
        BODY(3, s3z, s3r, s3n, s1z, s1r, s1n)
    }
#undef BODY
#undef GXLOAD

    if (wid == 0)
        hout[(g * 32 + b) * 64 + lane] = h;
}

// ---------------- Fallback (ws too small): fused single-wave. Slow but correct.
__global__ __launch_bounds__(64)
void gru_fused1(const float* __restrict__ x, const float* __restrict__ h0,
                const float* __restrict__ W, const float* __restrict__ U,
                const float* __restrict__ bi, const float* __restrict__ bh,
                float* __restrict__ out, float* __restrict__ hout)
{
    const int g = blockIdx.x >> 5, b = blockIdx.x & 31;
    const int lane = threadIdx.x;

    float u[64][3], w[64][3];
    {
        const float* Ug = U + (size_t)g * (64 * 192) + lane;
        const float* Wg = W + (size_t)g * (64 * 192) + lane;
        #pragma unroll
        for (int k = 0; k < 64; ++k) {
            u[k][0] = Ug[k * 192]; u[k][1] = Ug[k * 192 + 64]; u[k][2] = Ug[k * 192 + 128];
            w[k][0] = Wg[k * 192]; w[k][1] = Wg[k * 192 + 64]; w[k][2] = Wg[k * 192 + 128];
        }
    }
    const float biz = bi[g * 192 + lane], bir = bi[g * 192 + 64 + lane], bin_ = bi[g * 192 + 128 + lane];
    const float bhz = bh[g * 192 + lane], bhr = bh[g * 192 + 64 + lane], bhn = bh[g * 192 + 128 + lane];

    float h = h0[(g * 32 + b) * 64 + lane];
    const float* xp = x + (size_t)b * (TS * 512) + g * 64 + lane;
    float* op = out + (size_t)b * (TS * 512) + g * 64 + lane;

    for (int t = 0; t < TS; ++t) {
        const float xc = xp[(size_t)t * 512];
        float axz = biz, axr = bir, axn = bin_;
        float ahz = bhz, ahr = bhr, ahn = bhn;
        #pragma unroll
        for (int k = 0; k < 64; ++k) {
            const float sx = rl(xc, k);
            axz = fmaf(sx, w[k][0], axz);
            axr = fmaf(sx, w[k][1], axr);
            axn = fmaf(sx, w[k][2], axn);
        }
        #pragma unroll
        for (int k = 0; k < 64; ++k) {
            const float sh = rl(h, k);
            ahz = fmaf(sh, u[k][0], ahz);
            ahr = fmaf(sh, u[k][1], ahr);
            ahn = fmaf(sh, u[k][2], ahn);
        }
        const float z = fsig(axz + ahz);
        const float r = fsig(axr + ahr);
        const float n = ftanh(fmaf(r, ahn, axn));
        h = n + z * (h - n);
        op[(size_t)t * 512] = h;
    }
    hout[(g * 32 + b) * 64 + lane] = h;
}

extern "C" void kernel_launch(void* const* d_in, const int* in_sizes, int n_in,
                              void* d_out, int out_size, void* d_ws, size_t ws_size,
                              hipStream_t stream) {
    const float* x  = (const float*)d_in[0];
    const float* h0 = (const float*)d_in[1];
    const float* W  = (const float*)d_in[2];
    const float* U  = (const float*)d_in[3];
    const float* bi = (const float*)d_in[4];
    const float* bh = (const float*)d_in[5];
    float* out  = (float*)d_out;
    float* hout = out + (size_t)32 * TS * 512;

    const size_t gx_bytes = (size_t)8 * 32 * TS * 192 * sizeof(float);
    if (ws_size >= gx_bytes) {
        float* gxb = (float*)d_ws;
        hipLaunchKernelGGL(gx_gemm, dim3(8, 32, 8), dim3(512), 0, stream, x, W, bi, gxb);
        hipLaunchKernelGGL(gru_seq4, dim3(256), dim3(256), 0, stream, gxb, h0, U, bh, out, hout);
    } else {
        hipLaunchKernelGGL(gru_fused1, dim3(256), dim3(64), 0, stream,
                           x, h0, W, U, bi, bh, out, hout);
    }
}

// Round 7
// 494.741 us; speedup vs baseline: 1.9116x; 1.3842x over previous
//
#include <hip/hip_runtime.h>

#define TS 1000

__device__ __forceinline__ float rl(float v, int l) {
    return __int_as_float(__builtin_amdgcn_readlane(__float_as_int(v), l));
}
__device__ __forceinline__ float fsig(float x) {
    return __builtin_amdgcn_rcpf(1.0f + __expf(-x));
}
__device__ __forceinline__ float ftanh(float x) {
    return 1.0f - 2.0f * __builtin_amdgcn_rcpf(1.0f + __expf(2.0f * x));
}

// One block per (g,b) chain, 8 waves (2/SIMD):
//   wid 0-3 = consumers: U·h(t) partials, K-split 16 (round-6 structure).
//   wid 4-7 = producers: W·x(t+2) partials, K-split 16, x prefetched 2 deep
//             via inline-asm global_load + tied s_waitcnt vmcnt(2).
// One NON-draining s_barrier per step (loads stay in flight across it).
// Exchange: cpart mod-2 ring (same-step), ppart mod-4 ring (2 steps ahead);
// every slot is written pre-barrier and read post-barrier, with >=1 full
// barrier between the last read and the next rewrite. All 4 consumer waves
// compute gates redundantly in a fixed sum order -> bitwise-identical h.
// No workspace, no second kernel, no gx HBM round-trip.
__global__ __launch_bounds__(512)
__attribute__((amdgpu_waves_per_eu(2, 2)))
void gru_fused8(const float* __restrict__ x, const float* __restrict__ h0,
                const float* __restrict__ W, const float* __restrict__ U,
                const float* __restrict__ bi, const float* __restrict__ bh,
                float* __restrict__ out, float* __restrict__ hout)
{
    __shared__ float4 cpart[2][4][64];   // consumer partials, slot = t & 1
    __shared__ float4 ppart[4][4][64];   // producer partials, slot = t & 3 holds gx(t)

    const int tid  = threadIdx.x;
    const int lane = tid & 63;
    const int wid  = tid >> 6;
    const int role = wid >> 2;               // 0 = consumer, 1 = producer
    const int sw   = wid & 3;                // K-split index within role
    const int kb   = __builtin_amdgcn_readfirstlane(sw * 16);

    const int g = blockIdx.x >> 5, b = blockIdx.x & 31;

    // 48 stationary weights/lane: k-rows kb..kb+15, 3 gate columns.
    float w0[16], w1[16], w2[16];
    {
        const float* P = ((role == 0) ? U : W) + (size_t)g * (64 * 192) + (size_t)kb * 192 + lane;
        #pragma unroll
        for (int k = 0; k < 16; ++k) {
            w0[k] = P[k * 192];
            w1[k] = P[k * 192 + 64];
            w2[k] = P[k * 192 + 128];
        }
    }
    #pragma unroll
    for (int k = 0; k < 16; ++k)
        asm volatile("" : "+v"(w0[k]), "+v"(w1[k]), "+v"(w2[k]));

    // b_h folded into consumer sw0; b_i folded into producer sw0.
    float bz = 0.f, br = 0.f, bn = 0.f;
    if (sw == 0) {
        const float* bb = ((role == 0) ? bh : bi) + g * 192 + lane;
        bz = bb[0]; br = bb[64]; bn = bb[128];
    }

    float h = 0.f;
    if (role == 0) h = h0[(g * 32 + b) * 64 + lane];   // replicated, 4 consumer waves

    const float* xp = x + (size_t)b * (TS * 512) + g * 64 + lane;
    float* op = out + (size_t)b * (TS * 512) + g * 64 + lane;

    // Producer x register sets, written ONLY by asm loads, statically indexed
    // via the 4x-unrolled t-loop: set (time & 3) holds x(time).
    float xs0 = 0.f, xs1 = 0.f, xs2 = 0.f, xs3 = 0.f;

#define XLOAD(DST, T_)                                                        \
    { const float* pp_ = xp + (size_t)(T_) * 512;                             \
      asm volatile("global_load_dword %0, %1, off" : "=v"(DST) : "v"(pp_)); }

#define PPROD(XS, SLOT)                                                       \
    {                                                                         \
        float az = bz, ar = br, an = bn;                                      \
        _Pragma("unroll")                                                     \
        for (int k = 0; k < 16; ++k) {                                        \
            const float s = rl(XS, kb + k);                                   \
            az = fmaf(s, w0[k], az);                                          \
            ar = fmaf(s, w1[k], ar);                                          \
            an = fmaf(s, w2[k], an);                                          \
        }                                                                     \
        ppart[SLOT][sw][lane] = make_float4(az, ar, an, 0.f);                 \
    }

    // ---- producer prologue: gx(0) -> slot0, gx(1) -> slot1; x(2),x(3) in flight.
    if (role == 1) {
        XLOAD(xs0, 0) XLOAD(xs1, 1) XLOAD(xs2, 2) XLOAD(xs3, 3)
        asm volatile("s_waitcnt vmcnt(2)" : "+v"(xs0), "+v"(xs1));
        PPROD(xs0, 0)
        PPROD(xs1, 1)
    }

#define BODY(J, XS_USE, XS_FILL)                                              \
    {                                                                         \
        const int t = tt + (J);                                               \
        if (role == 1) {                                                      \
            /* issue x(t+4) into the set freed 2 bodies ago */                \
            int tl = t + 4; if (tl > TS - 1) tl = TS - 1;                     \
            XLOAD(XS_FILL, tl)                                                \
            /* x(t+2) guaranteed arrived: 3 outstanding -> wait to 2 */       \
            asm volatile("s_waitcnt vmcnt(2)" : "+v"(XS_USE));                \
            PPROD(XS_USE, (J + 2) & 3)                                        \
        } else {                                                              \
            float az = bz, ar = br, an = bn;                                  \
            _Pragma("unroll")                                                 \
            for (int k = 0; k < 16; ++k) {                                    \
                const float s = rl(h, kb + k);                                \
                az = fmaf(s, w0[k], az);                                      \
                ar = fmaf(s, w1[k], ar);                                      \
                an = fmaf(s, w2[k], an);                                      \
            }                                                                 \
            cpart[(J) & 1][sw][lane] = make_float4(az, ar, an, 0.f);          \
        }                                                                     \
        asm volatile("s_waitcnt lgkmcnt(0)" ::: "memory");                    \
        __builtin_amdgcn_sched_barrier(0);                                    \
        __builtin_amdgcn_s_barrier();          /* NO vmcnt drain */           \
        __builtin_amdgcn_sched_barrier(0);                                    \
        if (role == 0) {                                                      \
            const float4 c0 = cpart[(J) & 1][0][lane];                        \
            const float4 c1 = cpart[(J) & 1][1][lane];                        \
            const float4 c2 = cpart[(J) & 1][2][lane];                        \
            const float4 c3 = cpart[(J) & 1][3][lane];                        \
            const float4 q0 = ppart[(J) & 3][0][lane];                        \
            const float4 q1 = ppart[(J) & 3][1][lane];                        \
            const float4 q2 = ppart[(J) & 3][2][lane];                        \
            const float4 q3 = ppart[(J) & 3][3][lane];                        \
            const float ghz = ((c0.x + c1.x) + c2.x) + c3.x;                  \
            const float ghr = ((c0.y + c1.y) + c2.y) + c3.y;                  \
            const float ghn = ((c0.z + c1.z) + c2.z) + c3.z;                  \
            const float gxz = ((q0.x + q1.x) + q2.x) + q3.x;                  \
            const float gxr = ((q0.y + q1.y) + q2.y) + q3.y;                  \
            const float gxn = ((q0.z + q1.z) + q2.z) + q3.z;                  \
            const float z = fsig(gxz + ghz);                                  \
            const float r = fsig(gxr + ghr);                                  \
            const float n = ftanh(fmaf(r, ghn, gxn));   /* reset_after */     \
            h = n + z * (h - n);                                              \
            if (sw == 0) op[(size_t)t * 512] = h;                             \
        }                                                                     \
    }

    for (int tt = 0; tt < TS; tt += 4) {
        BODY(0, xs2, xs0)
        BODY(1, xs3, xs1)
        BODY(2, xs0, xs2)
        BODY(3, xs1, xs3)
    }
#undef BODY
#undef PPROD
#undef XLOAD

    if (role == 0 && sw == 0)
        hout[(g * 32 + b) * 64 + lane] = h;
}

extern "C" void kernel_launch(void* const* d_in, const int* in_sizes, int n_in,
                              void* d_out, int out_size, void* d_ws, size_t ws_size,
                              hipStream_t stream) {
    const float* x  = (const float*)d_in[0];
    const float* h0 = (const float*)d_in[1];
    const float* W  = (const float*)d_in[2];
    const float* U  = (const float*)d_in[3];
    const float* bi = (const float*)d_in[4];
    const float* bh = (const float*)d_in[5];
    float* out  = (float*)d_out;
    float* hout = out + (size_t)32 * TS * 512;
    hipLaunchKernelGGL(gru_fused8, dim3(256), dim3(512), 0, stream,
                       x, h0, W, U, bi, bh, out, hout);
}

// Round 8
// 484.691 us; speedup vs baseline: 1.9512x; 1.0207x over previous
//
#include <hip/hip_runtime.h>

#define TS 1000

__device__ __forceinline__ float rl(float v, int l) {
    return __int_as_float(__builtin_amdgcn_readlane(__float_as_int(v), l));
}
__device__ __forceinline__ float fsig(float x) {
    return __builtin_amdgcn_rcpf(1.0f + __expf(-x));
}
__device__ __forceinline__ float ftanh(float x) {
    return 1.0f - 2.0f * __builtin_amdgcn_rcpf(1.0f + __expf(2.0f * x));
}

// One block per (g,b) chain, 8 waves (2/SIMD):
//   wid 0-3 = consumers: U·h(t) partials, K-split 16.
//   wid 4-7 = producers: W·x(t+2) partials, K-split 16, x prefetched deep
//             via inline-asm global_load + tied s_waitcnt vmcnt(2).
//   producer sw0 additionally PRE-REDUCES the 4 gx partials of step t+1
//   into psum[(t+1)&3] (producers have issue slack; consumers are the
//   critical path). Consumer post-barrier reads: 4 cpart + 1 psum (was 8).
// One NON-draining s_barrier per step; loads stay in flight across it.
// Ring audit: every LDS slot is written pre-barrier and read post-barrier
// with >=2 barriers between last read and rewrite:
//   cpart[t&1]: write t, read t, rewrite t+2.
//   ppart[s]: write t (s=(t+2)&3), reducer-read t+1, rewrite t+4.
//   psum[s]:  write t (s=(t+1)&3), consumer-read t+1, rewrite t+4.
// All 4 consumer waves compute gates redundantly in a fixed sum order
// -> bitwise-identical h replicas -> deterministic across replays.
__global__ __launch_bounds__(512)
__attribute__((amdgpu_waves_per_eu(2, 2)))
void gru_fused8(const float* __restrict__ x, const float* __restrict__ h0,
                const float* __restrict__ W, const float* __restrict__ U,
                const float* __restrict__ bi, const float* __restrict__ bh,
                float* __restrict__ out, float* __restrict__ hout)
{
    __shared__ float4 cpart[2][4][64];   // consumer partials, slot = t & 1
    __shared__ float4 ppart[4][4][64];   // producer partials, slot s holds gx(s mod)
    __shared__ float4 psum[4][64];       // pre-reduced gx, slot = t & 3

    const int tid  = threadIdx.x;
    const int lane = tid & 63;
    const int wid  = tid >> 6;
    const int role = wid >> 2;               // 0 = consumer, 1 = producer
    const int sw   = wid & 3;                // K-split index within role
    const int kb   = __builtin_amdgcn_readfirstlane(sw * 16);

    const int g = blockIdx.x >> 5, b = blockIdx.x & 31;

    // 48 stationary weights/lane: k-rows kb..kb+15, 3 gate columns.
    float w0[16], w1[16], w2[16];
    {
        const float* P = ((role == 0) ? U : W) + (size_t)g * (64 * 192) + (size_t)kb * 192 + lane;
        #pragma unroll
        for (int k = 0; k < 16; ++k) {
            w0[k] = P[k * 192];
            w1[k] = P[k * 192 + 64];
            w2[k] = P[k * 192 + 128];
        }
    }
    #pragma unroll
    for (int k = 0; k < 16; ++k)
        asm volatile("" : "+v"(w0[k]), "+v"(w1[k]), "+v"(w2[k]));

    // b_h folded into consumer sw0; b_i folded into producer sw0.
    float bz = 0.f, br = 0.f, bn = 0.f;
    if (sw == 0) {
        const float* bb = ((role == 0) ? bh : bi) + g * 192 + lane;
        bz = bb[0]; br = bb[64]; bn = bb[128];
    }

    float h = 0.f;
    if (role == 0) h = h0[(g * 32 + b) * 64 + lane];   // replicated, 4 consumer waves

    const float* xp = x + (size_t)b * (TS * 512) + g * 64 + lane;
    float* op = out + (size_t)b * (TS * 512) + g * 64 + lane;

    // Producer x register sets, written ONLY by asm loads, statically indexed
    // via the 4x-unrolled t-loop: set (time & 3) holds x(time).
    float xs0 = 0.f, xs1 = 0.f, xs2 = 0.f, xs3 = 0.f;

#define XLOAD(DST, T_)                                                        \
    { const float* pp_ = xp + (size_t)(T_) * 512;                             \
      asm volatile("global_load_dword %0, %1, off" : "=v"(DST) : "v"(pp_)); }

#define PPROD(XS, SLOT)                                                       \
    {                                                                         \
        float az = bz, ar = br, an = bn;                                      \
        _Pragma("unroll")                                                     \
        for (int k = 0; k < 16; ++k) {                                        \
            const float s = rl(XS, kb + k);                                   \
            az = fmaf(s, w0[k], az);                                          \
            ar = fmaf(s, w1[k], ar);                                          \
            an = fmaf(s, w2[k], an);                                          \
        }                                                                     \
        ppart[SLOT][sw][lane] = make_float4(az, ar, an, 0.f);                 \
    }

#define PREDUCE(SLOT)                                                         \
    {                                                                         \
        const float4 q0 = ppart[SLOT][0][lane];                               \
        const float4 q1 = ppart[SLOT][1][lane];                               \
        const float4 q2 = ppart[SLOT][2][lane];                               \
        const float4 q3 = ppart[SLOT][3][lane];                               \
        psum[SLOT][lane] = make_float4(((q0.x + q1.x) + q2.x) + q3.x,         \
                                       ((q0.y + q1.y) + q2.y) + q3.y,         \
                                       ((q0.z + q1.z) + q2.z) + q3.z, 0.f);   \
    }

    // ---- producer prologue: gx(0)->ppart[0], gx(1)->ppart[1]; x(2),x(3) in flight.
    if (role == 1) {
        XLOAD(xs0, 0) XLOAD(xs1, 1) XLOAD(xs2, 2) XLOAD(xs3, 3)
        asm volatile("s_waitcnt vmcnt(2)" : "+v"(xs0), "+v"(xs1));
        PPROD(xs0, 0)
        PPROD(xs1, 1)
    }
    asm volatile("s_waitcnt lgkmcnt(0)" ::: "memory");
    __builtin_amdgcn_s_barrier();
    // reducer prologue: psum[0] = sum of gx(0) partials (visible after barrier(0)).
    if (role == 1 && sw == 0) PREDUCE(0)

#define BODY(J, XS_USE, XS_FILL)                                              \
    {                                                                         \
        const int t = tt + (J);                                               \
        if (role == 1) {                                                      \
            /* issue x(t+4) into the set freed 2 bodies ago */                \
            int tl = t + 4; if (tl > TS - 1) tl = TS - 1;                     \
            XLOAD(XS_FILL, tl)                                                \
            /* x(t+2) guaranteed arrived: 3 outstanding -> wait to 2 */       \
            asm volatile("s_waitcnt vmcnt(2)" : "+v"(XS_USE));                \
            PPROD(XS_USE, (J + 2) & 3)                                        \
            if (sw == 0) PREDUCE((J + 1) & 3)   /* pre-reduce gx(t+1) */      \
        } else {                                                              \
            float az = bz, ar = br, an = bn;                                  \
            _Pragma("unroll")                                                 \
            for (int k = 0; k < 16; ++k) {                                    \
                const float s = rl(h, kb + k);                                \
                az = fmaf(s, w0[k], az);                                      \
                ar = fmaf(s, w1[k], ar);                                      \
                an = fmaf(s, w2[k], an);                                      \
            }                                                                 \
            cpart[(J) & 1][sw][lane] = make_float4(az, ar, an, 0.f);          \
        }                                                                     \
        asm volatile("s_waitcnt lgkmcnt(0)" ::: "memory");                    \
        __builtin_amdgcn_sched_barrier(0);                                    \
        __builtin_amdgcn_s_barrier();          /* NO vmcnt drain */           \
        __builtin_amdgcn_sched_barrier(0);                                    \
        if (role == 0) {                                                      \
            __builtin_amdgcn_s_setprio(1);     /* consumer = critical path */ \
            const float4 c0 = cpart[(J) & 1][0][lane];                        \
            const float4 c1 = cpart[(J) & 1][1][lane];                        \
            const float4 c2 = cpart[(J) & 1][2][lane];                        \
            const float4 c3 = cpart[(J) & 1][3][lane];                        \
            const float4 q  = psum[(J) & 3][lane];                            \
            const float ghz = ((c0.x + c1.x) + c2.x) + c3.x;                  \
            const float ghr = ((c0.y + c1.y) + c2.y) + c3.y;                  \
            const float ghn = ((c0.z + c1.z) + c2.z) + c3.z;                  \
            const float z = fsig(q.x + ghz);                                  \
            const float r = fsig(q.y + ghr);                                  \
            const float n = ftanh(fmaf(r, ghn, q.z));   /* reset_after */     \
            h = n + z * (h - n);                                              \
            __builtin_amdgcn_s_setprio(0);                                    \
            if (sw == 0) op[(size_t)t * 512] = h;                             \
        }                                                                     \
    }

    for (int tt = 0; tt < TS; tt += 4) {
        BODY(0, xs2, xs0)
        BODY(1, xs3, xs1)
        BODY(2, xs0, xs2)
        BODY(3, xs1, xs3)
    }
#undef BODY
#undef PREDUCE
#undef PPROD
#undef XLOAD

    if (role == 0 && sw == 0)
        hout[(g * 32 + b) * 64 + lane] = h;
}

extern "C" void kernel_launch(void* const* d_in, const int* in_sizes, int n_in,
                              void* d_out, int out_size, void* d_ws, size_t ws_size,
                              hipStream_t stream) {
    const float* x  = (const float*)d_in[0];
    const float* h0 = (const float*)d_in[1];
    const float* W  = (const float*)d_in[2];
    const float* U  = (const float*)d_in[3];
    const float* bi = (const float*)d_in[4];
    const float* bh = (const float*)d_in[5];
    float* out  = (float*)d_out;
    float* hout = out + (size_t)32 * TS * 512;
    hipLaunchKernelGGL(gru_fused8, dim3(256), dim3(512), 0, stream,
                       x, h0, W, U, bi, bh, out, hout);
}